// Round 2
// baseline (176.451 us; speedup 1.0000x reference)
//
#include <hip/hip_runtime.h>
#include <math.h>

// Problem constants (from reference)
#define B_  64
#define S_  2048
#define E_  300
#define H_  150
#define C_  34
#define CHUNK 128
#define NCHUNK (S_ / CHUNK)   // 16
#define WAVES 4               // 256-thread blocks

// One gather pass with online softmax: for each (b, chunk of 128 tokens),
// wave w handles tokens w+4k. Per token: load 1200B embedding row (float4
// slots: lane i -> slot i, lanes 0..10 -> slot 64+i), dot with per-b query,
// butterfly all-reduce, online-softmax accumulate h (unnormalized, base m).
// Block combines its 4 waves' partials in LDS and writes (m, l, h[300]).
__global__ __launch_bounds__(256) void attn_pass(
    const int* __restrict__ x, const float* __restrict__ emb,
    const float* __restrict__ qmat, int q_stride, float scale,
    float* __restrict__ h_part, float* __restrict__ m_part,
    float* __restrict__ l_part)
{
    const int b     = blockIdx.y;
    const int chunk = blockIdx.x;
    const int tid   = threadIdx.x;
    const int w     = tid >> 6;
    const int lane  = tid & 63;

    // Per-lane query fragment (pre-scaled): slot `lane` + slot `64+lane`
    const float4* qp = (const float4*)(qmat + (size_t)b * q_stride);
    float4 q0 = qp[lane];
    float4 q1 = make_float4(0.f, 0.f, 0.f, 0.f);
    if (lane < 11) q1 = qp[64 + lane];
    q0.x *= scale; q0.y *= scale; q0.z *= scale; q0.w *= scale;
    q1.x *= scale; q1.y *= scale; q1.z *= scale; q1.w *= scale;

    // Prefetch this wave's 32 token indices (token t_local = w + 4k)
    const int base = b * S_ + chunk * CHUNK;
    int myidx = 0;
    if (lane < 32) myidx = x[base + w + 4 * lane];

    float  m = -INFINITY, l = 0.f;
    float4 a0 = make_float4(0.f, 0.f, 0.f, 0.f);
    float4 a1 = make_float4(0.f, 0.f, 0.f, 0.f);

    for (int k = 0; k < 32; ++k) {
        const int row = __shfl(myidx, k);
        const float4* rp = (const float4*)(emb + (size_t)row * E_);
        float4 r0 = rp[lane];
        float4 r1 = make_float4(0.f, 0.f, 0.f, 0.f);
        if (lane < 11) r1 = rp[64 + lane];

        float d = q0.x * r0.x + q0.y * r0.y + q0.z * r0.z + q0.w * r0.w
                + q1.x * r1.x + q1.y * r1.y + q1.z * r1.z + q1.w * r1.w;
        #pragma unroll
        for (int off = 32; off > 0; off >>= 1) d += __shfl_xor(d, off);

        // online softmax (wave-uniform branch; rare after warm-up)
        if (d > m) {
            float c = __expf(m - d);   // first token: exp(-inf)=0 zeroes l/acc
            l *= c;
            a0.x *= c; a0.y *= c; a0.z *= c; a0.w *= c;
            a1.x *= c; a1.y *= c; a1.z *= c; a1.w *= c;
            m = d;
        }
        float p = __expf(d - m);
        l += p;
        a0.x += p * r0.x; a0.y += p * r0.y; a0.z += p * r0.z; a0.w += p * r0.w;
        a1.x += p * r1.x; a1.y += p * r1.y; a1.z += p * r1.z; a1.w += p * r1.w;
    }

    // Combine 4 waves in LDS
    __shared__ float sm[WAVES], sl[WAVES];
    __shared__ __align__(16) float sacc[WAVES][304];  // 304 = 16B-multiple rows
    ((float4*)sacc[w])[lane] = a0;
    if (lane < 11) ((float4*)sacc[w])[64 + lane] = a1;
    if (lane == 0) { sm[w] = m; sl[w] = l; }
    __syncthreads();

    // BUGFIX (round 1): E_=300 > blockDim=256 — must LOOP, not `if (tid<E_)`.
    // Elements 256..299 were previously never written (stayed 0xAA poison).
    const float mb = fmaxf(fmaxf(sm[0], sm[1]), fmaxf(sm[2], sm[3]));
    const int pi = b * NCHUNK + chunk;
    for (int j = tid; j < E_; j += 256) {
        float h = 0.f;
        #pragma unroll
        for (int c = 0; c < WAVES; ++c)
            h += __expf(sm[c] - mb) * sacc[c][j];
        h_part[(size_t)pi * E_ + j] = h;
    }
    if (tid == 0) {
        float lb = 0.f;
        #pragma unroll
        for (int c = 0; c < WAVES; ++c) lb += __expf(sm[c] - mb) * sl[c];
        m_part[pi] = mb; l_part[pi] = lb;
    }
}

// Reduce NCHUNK partials per batch row -> normalized h[b][300]
__global__ __launch_bounds__(320) void combine_pass(
    const float* __restrict__ h_part, const float* __restrict__ m_part,
    const float* __restrict__ l_part, float* __restrict__ hout)
{
    const int b = blockIdx.x, tid = threadIdx.x;
    __shared__ float sm[NCHUNK], sl[NCHUNK];
    if (tid < NCHUNK) { sm[tid] = m_part[b * NCHUNK + tid];
                        sl[tid] = l_part[b * NCHUNK + tid]; }
    __syncthreads();
    if (tid < E_) {
        float M = -INFINITY;
        #pragma unroll
        for (int c = 0; c < NCHUNK; ++c) M = fmaxf(M, sm[c]);
        float L = 0.f, h = 0.f;
        #pragma unroll
        for (int c = 0; c < NCHUNK; ++c) {
            float wc = __expf(sm[c] - M);
            L += wc * sl[c];
            h += wc * h_part[((size_t)b * NCHUNK + c) * E_ + tid];
        }
        hout[b * E_ + tid] = h / L;
    }
}

// v2[b] = (h1[b] @ W) @ W^T   — the k2-elimination trick
__global__ __launch_bounds__(320) void qv_kernel(
    const float* __restrict__ h1, const float* __restrict__ W,
    float* __restrict__ v2)
{
    const int b = blockIdx.x, tid = threadIdx.x;
    __shared__ float sh[E_], sq[H_];
    if (tid < E_) sh[tid] = h1[b * E_ + tid];
    __syncthreads();
    if (tid < H_) {
        float acc = 0.f;
        for (int e = 0; e < E_; ++e) acc += sh[e] * W[e * H_ + tid];
        sq[tid] = acc;
    }
    __syncthreads();
    if (tid < E_) {
        float acc = 0.f;
        const float* wr = W + (size_t)tid * H_;
        for (int h = 0; h < H_; ++h) acc += sq[h] * wr[h];
        v2[b * E_ + tid] = acc;
    }
}

// scores[b] = [h1;h2] @ W_out + bias
__global__ __launch_bounds__(256) void scores_kernel(
    const float* __restrict__ h1, const float* __restrict__ h2,
    const float* __restrict__ Wout, const float* __restrict__ bias,
    float* __restrict__ out)
{
    const int b = blockIdx.x, tid = threadIdx.x;
    const int w = tid >> 6, lane = tid & 63;
    __shared__ float hh[2 * E_];
    for (int j = tid; j < 2 * E_; j += 256)
        hh[j] = (j < E_) ? h1[b * E_ + j] : h2[b * E_ + (j - E_)];
    __syncthreads();
    for (int c = w; c < C_; c += 4) {
        float p = 0.f;
        for (int e = lane; e < 2 * E_; e += 64)
            p += hh[e] * Wout[(size_t)e * C_ + c];
        #pragma unroll
        for (int off = 32; off > 0; off >>= 1) p += __shfl_xor(p, off);
        if (lane == 0) out[b * C_ + c] = p + bias[c];
    }
}

extern "C" void kernel_launch(void* const* d_in, const int* in_sizes, int n_in,
                              void* d_out, int out_size, void* d_ws, size_t ws_size,
                              hipStream_t stream) {
    const int*   x     = (const int*)  d_in[0];   // [64,2048] int32
    const float* emb   = (const float*)d_in[1];   // [50000,300]
    const float* query = (const float*)d_in[2];   // [1,300]
    const float* Watt  = (const float*)d_in[3];   // [300,150]
    const float* Wout  = (const float*)d_in[4];   // [600,34]
    const float* bias  = (const float*)d_in[5];   // [34]
    float* out = (float*)d_out;                   // [64,34]

    // Workspace layout (floats); total ~367K floats = 1.47 MB
    float* ws     = (float*)d_ws;
    float* h_part = ws;                           // B*NCHUNK*E = 307200
    float* m_part = h_part + (size_t)B_ * NCHUNK * E_;  // 1024
    float* l_part = m_part + B_ * NCHUNK;               // 1024
    float* h1     = l_part + B_ * NCHUNK;               // 19200
    float* h2     = h1 + B_ * E_;                       // 19200
    float* v2     = h2 + B_ * E_;                       // 19200

    const float scale1 = 1.0f / sqrtf((float)E_);
    dim3 grid(NCHUNK, B_), blk(256);

    // Stage 1: q = broadcast query (stride 0), scaled by 1/sqrt(E)
    attn_pass<<<grid, blk, 0, stream>>>(x, emb, query, 0, scale1,
                                        h_part, m_part, l_part);
    combine_pass<<<B_, 320, 0, stream>>>(h_part, m_part, l_part, h1);
    // v2 = (h1 @ W) @ W^T
    qv_kernel<<<B_, 320, 0, stream>>>(h1, Watt, v2);
    // Stage 2: per-b query v2, no scale (reference has none)
    attn_pass<<<grid, blk, 0, stream>>>(x, emb, v2, E_, 1.0f,
                                        h_part, m_part, l_part);
    combine_pass<<<B_, 320, 0, stream>>>(h_part, m_part, l_part, h2);
    scores_kernel<<<B_, 256, 0, stream>>>(h1, h2, Wout, bias, out);
}

// Round 3
// 170.973 us; speedup vs baseline: 1.0320x; 1.0320x over previous
//
#include <hip/hip_runtime.h>
#include <math.h>

// Problem constants (from reference)
#define B_  64
#define S_  2048
#define E_  300
#define H_  150
#define C_  34
#define CHUNK 128
#define NCHUNK (S_ / CHUNK)   // 16
#define WAVES 4               // 256-thread blocks

// Gather pass with online softmax, 4 tokens per iteration for MLP.
// Wave w handles tokens w+4k of its 128-token chunk. Per group of 4 tokens:
// issue 8 row loads back-to-back, 4 dots, 4 interleaved butterfly reduces,
// one branchless grouped softmax rescale. Block combines 4 waves via LDS and
// writes per-chunk (m, l, unnormalized h[300]).
__global__ __launch_bounds__(256, 4) void attn_pass(
    const int* __restrict__ x, const float* __restrict__ emb,
    const float* __restrict__ qmat, int q_stride, float scale,
    float* __restrict__ h_part, float* __restrict__ m_part,
    float* __restrict__ l_part)
{
    const int b     = blockIdx.y;
    const int chunk = blockIdx.x;
    const int tid   = threadIdx.x;
    const int w     = tid >> 6;
    const int lane  = tid & 63;

    // Per-lane query fragment (pre-scaled): float4 slot `lane` + slot 64+lane
    const float4* qp = (const float4*)(qmat + (size_t)b * q_stride);
    float4 q0 = qp[lane];
    float4 q1 = make_float4(0.f, 0.f, 0.f, 0.f);
    if (lane < 11) q1 = qp[64 + lane];
    q0.x *= scale; q0.y *= scale; q0.z *= scale; q0.w *= scale;
    q1.x *= scale; q1.y *= scale; q1.z *= scale; q1.w *= scale;

    // Wave's 32 token indices live in lanes 0..31
    const int base = b * S_ + chunk * CHUNK;
    int myidx = 0;
    if (lane < 32) myidx = x[base + w + 4 * lane];

    float  m = -INFINITY, l = 0.f;
    float4 a0 = make_float4(0.f, 0.f, 0.f, 0.f);
    float4 a1 = make_float4(0.f, 0.f, 0.f, 0.f);

    for (int g = 0; g < 8; ++g) {
        // --- 8 independent loads in flight ---
        float4 r0[4], r1[4];
        #pragma unroll
        for (int t = 0; t < 4; ++t) {
            const int row = __shfl(myidx, 4 * g + t);
            const float4* rp = (const float4*)(emb + (size_t)row * E_);
            r0[t] = rp[lane];
            r1[t] = make_float4(0.f, 0.f, 0.f, 0.f);
            if (lane < 11) r1[t] = rp[64 + lane];
        }
        // --- 4 dots ---
        float d[4];
        #pragma unroll
        for (int t = 0; t < 4; ++t)
            d[t] = q0.x * r0[t].x + q0.y * r0[t].y + q0.z * r0[t].z + q0.w * r0[t].w
                 + q1.x * r1[t].x + q1.y * r1[t].y + q1.z * r1[t].z + q1.w * r1[t].w;
        // --- 4 butterfly reduces, interleaved (independent DS chains) ---
        #pragma unroll
        for (int off = 32; off > 0; off >>= 1) {
            #pragma unroll
            for (int t = 0; t < 4; ++t) d[t] += __shfl_xor(d[t], off);
        }
        // --- branchless grouped online-softmax update ---
        const float gm = fmaxf(fmaxf(d[0], d[1]), fmaxf(d[2], d[3]));
        const float mn = fmaxf(m, gm);
        const float c  = __expf(m - mn);        // first group: exp(-inf)=0
        const float p0 = __expf(d[0] - mn), p1 = __expf(d[1] - mn);
        const float p2 = __expf(d[2] - mn), p3 = __expf(d[3] - mn);
        l = l * c + ((p0 + p1) + (p2 + p3));
        a0.x = a0.x * c + p0 * r0[0].x + p1 * r0[1].x + p2 * r0[2].x + p3 * r0[3].x;
        a0.y = a0.y * c + p0 * r0[0].y + p1 * r0[1].y + p2 * r0[2].y + p3 * r0[3].y;
        a0.z = a0.z * c + p0 * r0[0].z + p1 * r0[1].z + p2 * r0[2].z + p3 * r0[3].z;
        a0.w = a0.w * c + p0 * r0[0].w + p1 * r0[1].w + p2 * r0[2].w + p3 * r0[3].w;
        a1.x = a1.x * c + p0 * r1[0].x + p1 * r1[1].x + p2 * r1[2].x + p3 * r1[3].x;
        a1.y = a1.y * c + p0 * r1[0].y + p1 * r1[1].y + p2 * r1[2].y + p3 * r1[3].y;
        a1.z = a1.z * c + p0 * r1[0].z + p1 * r1[1].z + p2 * r1[2].z + p3 * r1[3].z;
        a1.w = a1.w * c + p0 * r1[0].w + p1 * r1[1].w + p2 * r1[2].w + p3 * r1[3].w;
        m = mn;
    }

    // Combine 4 waves in LDS
    __shared__ float sm[WAVES], sl[WAVES];
    __shared__ __align__(16) float sacc[WAVES][304];
    ((float4*)sacc[w])[lane] = a0;
    if (lane < 11) ((float4*)sacc[w])[64 + lane] = a1;
    if (lane == 0) { sm[w] = m; sl[w] = l; }
    __syncthreads();

    // E_=300 > 256 threads: must LOOP (round-1 bugfix)
    const float mb = fmaxf(fmaxf(sm[0], sm[1]), fmaxf(sm[2], sm[3]));
    const int pi = b * NCHUNK + chunk;
    for (int j = tid; j < E_; j += 256) {
        float h = 0.f;
        #pragma unroll
        for (int c = 0; c < WAVES; ++c)
            h += __expf(sm[c] - mb) * sacc[c][j];
        h_part[(size_t)pi * E_ + j] = h;
    }
    if (tid == 0) {
        float lb = 0.f;
        #pragma unroll
        for (int c = 0; c < WAVES; ++c) lb += __expf(sm[c] - mb) * sl[c];
        m_part[pi] = mb; l_part[pi] = lb;
    }
}

// Fused: combine NCHUNK partials -> h1[b], then v2[b] = (h1 @ W) @ W^T
__global__ __launch_bounds__(320) void combine_qv(
    const float* __restrict__ h_part, const float* __restrict__ m_part,
    const float* __restrict__ l_part, const float* __restrict__ W,
    float* __restrict__ h1out, float* __restrict__ v2out)
{
    const int b = blockIdx.x, tid = threadIdx.x;
    __shared__ float sm[NCHUNK], sl[NCHUNK], sh[E_], sq[H_];
    if (tid < NCHUNK) { sm[tid] = m_part[b * NCHUNK + tid];
                        sl[tid] = l_part[b * NCHUNK + tid]; }
    __syncthreads();
    if (tid < E_) {
        float M = -INFINITY;
        #pragma unroll
        for (int c = 0; c < NCHUNK; ++c) M = fmaxf(M, sm[c]);
        float L = 0.f, h = 0.f;
        #pragma unroll
        for (int c = 0; c < NCHUNK; ++c) {
            const float wc = __expf(sm[c] - M);
            L += wc * sl[c];
            h += wc * h_part[((size_t)b * NCHUNK + c) * E_ + tid];
        }
        const float v = h / L;
        sh[tid] = v;
        h1out[b * E_ + tid] = v;
    }
    __syncthreads();
    if (tid < H_) {
        float acc = 0.f;
        for (int e = 0; e < E_; ++e) acc += sh[e] * W[e * H_ + tid];
        sq[tid] = acc;
    }
    __syncthreads();
    if (tid < E_) {
        float acc = 0.f;
        const float* wr = W + (size_t)tid * H_;
        for (int h = 0; h < H_; ++h) acc += sq[h] * wr[h];
        v2out[b * E_ + tid] = acc;
    }
}

// Fused: combine NCHUNK partials -> h2[b], then scores = [h1;h2]@Wout + bias
__global__ __launch_bounds__(320) void combine_scores(
    const float* __restrict__ h_part, const float* __restrict__ m_part,
    const float* __restrict__ l_part, const float* __restrict__ h1,
    const float* __restrict__ Wout, const float* __restrict__ bias,
    float* __restrict__ out)
{
    const int b = blockIdx.x, tid = threadIdx.x;
    const int w = tid >> 6, lane = tid & 63;
    __shared__ float sm[NCHUNK], sl[NCHUNK];
    __shared__ float hh[2 * E_];
    if (tid < NCHUNK) { sm[tid] = m_part[b * NCHUNK + tid];
                        sl[tid] = l_part[b * NCHUNK + tid]; }
    if (tid < E_) hh[tid] = h1[b * E_ + tid];
    __syncthreads();
    if (tid < E_) {
        float M = -INFINITY;
        #pragma unroll
        for (int c = 0; c < NCHUNK; ++c) M = fmaxf(M, sm[c]);
        float L = 0.f, h = 0.f;
        #pragma unroll
        for (int c = 0; c < NCHUNK; ++c) {
            const float wc = __expf(sm[c] - M);
            L += wc * sl[c];
            h += wc * h_part[((size_t)b * NCHUNK + c) * E_ + tid];
        }
        hh[E_ + tid] = h / L;
    }
    __syncthreads();
    // 5 waves cover 34 classes
    for (int c = w; c < C_; c += 5) {
        float p = 0.f;
        for (int e = lane; e < 2 * E_; e += 64)
            p += hh[e] * Wout[(size_t)e * C_ + c];
        #pragma unroll
        for (int off = 32; off > 0; off >>= 1) p += __shfl_xor(p, off);
        if (lane == 0) out[b * C_ + c] = p + bias[c];
    }
}

extern "C" void kernel_launch(void* const* d_in, const int* in_sizes, int n_in,
                              void* d_out, int out_size, void* d_ws, size_t ws_size,
                              hipStream_t stream) {
    const int*   x     = (const int*)  d_in[0];   // [64,2048] int32
    const float* emb   = (const float*)d_in[1];   // [50000,300]
    const float* query = (const float*)d_in[2];   // [1,300]
    const float* Watt  = (const float*)d_in[3];   // [300,150]
    const float* Wout  = (const float*)d_in[4];   // [600,34]
    const float* bias  = (const float*)d_in[5];   // [34]
    float* out = (float*)d_out;                   // [64,34]

    // Workspace layout (floats)
    float* ws     = (float*)d_ws;
    float* h_part = ws;                                 // B*NCHUNK*E = 307200
    float* m_part = h_part + (size_t)B_ * NCHUNK * E_;  // 1024
    float* l_part = m_part + B_ * NCHUNK;               // 1024
    float* h1     = l_part + B_ * NCHUNK;               // 19200
    float* v2     = h1 + B_ * E_;                       // 19200

    const float scale1 = 1.0f / sqrtf((float)E_);
    dim3 grid(NCHUNK, B_), blk(256);

    // Stage 1: broadcast query (stride 0), scaled by 1/sqrt(E)
    attn_pass<<<grid, blk, 0, stream>>>(x, emb, query, 0, scale1,
                                        h_part, m_part, l_part);
    // h1 + v2 = (h1@W)@W^T in one 64-block kernel
    combine_qv<<<B_, 320, 0, stream>>>(h_part, m_part, l_part, Watt, h1, v2);
    // Stage 2: per-b query v2, no scale (reference has none)
    attn_pass<<<grid, blk, 0, stream>>>(x, emb, v2, E_, 1.0f,
                                        h_part, m_part, l_part);
    // h2 + final scores in one 64-block kernel
    combine_scores<<<B_, 320, 0, stream>>>(h_part, m_part, l_part, h1,
                                           Wout, bias, out);
}